// Round 1
// baseline (4164.475 us; speedup 1.0000x reference)
//
#include <hip/hip_runtime.h>

#define B_ 4
#define T_ 1024
#define E_ 1024
#define H_ 16
#define HD_ 64
#define L_ 8
#define V_ 32000
#define FF_ 4096
#define M_ (B_*T_)

typedef unsigned short u16;
typedef __attribute__((ext_vector_type(8))) short bf16x8;   // 8 bf16 = 4 VGPR
typedef __attribute__((ext_vector_type(4))) float f32x4;

#define AS1V(p) ((__attribute__((address_space(1))) void*)(p))
#define AS3V(p) ((__attribute__((address_space(3))) void*)(p))

__device__ __forceinline__ u16 f2bf(float f) {              // RNE f32->bf16
    unsigned int u = __float_as_uint(f);
    u += 0x7FFFu + ((u >> 16) & 1u);
    return (u16)(u >> 16);
}
__device__ __forceinline__ float bf2f(u16 v) {
    return __uint_as_float(((unsigned int)v) << 16);
}
__device__ __forceinline__ float ldf(const float* p, long i) { return p[i]; }
__device__ __forceinline__ float ldf(const u16*   p, long i) { return bf2f(p[i]); }

// ---------------- batched tiled transpose:  dst[N][K](bf16) = src[K][N] ----------------
// batch z: zb=z/ZH, zh=z%ZH ; src += zb*szb+zh*szh ; dst += zb*dzb+zh*dzh
template<typename ST>
__global__ void k_transpose(const ST* __restrict__ src, u16* __restrict__ dst,
                            int K, int N, long srs, long drs,
                            int ZH, long szb, long szh, long dzb, long dzh)
{
    __shared__ float tile[32][33];
    int z = blockIdx.z; int zb = z / ZH, zh = z % ZH;
    const ST* s = src + (long)zb*szb + (long)zh*szh;
    u16* d = dst + (long)zb*dzb + (long)zh*dzh;
    int k0 = blockIdx.y * 32, n0 = blockIdx.x * 32;
    int tx = threadIdx.x, ty = threadIdx.y;
    for (int i = ty; i < 32; i += 8) {
        int k = k0 + i, n = n0 + tx;
        tile[i][tx] = (k < K && n < N) ? ldf(s, (long)k*srs + n) : 0.f;
    }
    __syncthreads();
    for (int i = ty; i < 32; i += 8) {
        int n = n0 + i, k = k0 + tx;
        if (n < N && k < K) d[(long)n*drs + k] = f2bf(tile[tx][i]);
    }
}

// ---------------- token+pos embedding -> h (f32) ----------------
__global__ void k_embed(const int* __restrict__ x, const float* __restrict__ tok,
                        const float* __restrict__ pos, float* __restrict__ h)
{
    long i = (long)blockIdx.x * 256 + threadIdx.x;      // one float4 per thread
    int e4 = (int)(i & (E_/4 - 1));
    long bt = i >> 8;
    int t = (int)(bt & (T_ - 1));
    int id = x[bt];
    float4 a = *(const float4*)(tok + (long)id*E_ + e4*4);
    float4 p = *(const float4*)(pos + (long)t*E_ + e4*4);
    float4 o; o.x=a.x+p.x; o.y=a.y+p.y; o.z=a.z+p.z; o.w=a.w+p.w;
    *(float4*)(h + bt*E_ + e4*4) = o;
}

// ---------------- layernorm (row of E=1024, block=256) -> bf16 ----------------
__global__ void k_ln(const float* __restrict__ in, const float* __restrict__ g,
                     const float* __restrict__ b, u16* __restrict__ out)
{
    int row = blockIdx.x, tid = threadIdx.x;
    float4 v = *(const float4*)(in + (long)row*E_ + tid*4);
    float s = v.x + v.y + v.z + v.w;
    float ss = v.x*v.x + v.y*v.y + v.z*v.z + v.w*v.w;
    #pragma unroll
    for (int o = 32; o; o >>= 1) { s += __shfl_down(s, o); ss += __shfl_down(ss, o); }
    __shared__ float r0[4], r1[4];
    if ((tid & 63) == 0) { r0[tid >> 6] = s; r1[tid >> 6] = ss; }
    __syncthreads();
    s  = r0[0] + r0[1] + r0[2] + r0[3];
    ss = r1[0] + r1[1] + r1[2] + r1[3];
    float mean = s * (1.f/E_);
    float rstd = rsqrtf(ss * (1.f/E_) - mean*mean + 1e-5f);
    float4 gv = *(const float4*)(g + tid*4);
    float4 bv = *(const float4*)(b + tid*4);
    ushort4 pk;
    pk.x = f2bf((v.x - mean)*rstd*gv.x + bv.x);
    pk.y = f2bf((v.y - mean)*rstd*gv.y + bv.y);
    pk.z = f2bf((v.z - mean)*rstd*gv.z + bv.z);
    pk.w = f2bf((v.w - mean)*rstd*gv.w + bv.w);
    *(ushort4*)(out + (long)row*E_ + tid*4) = pk;
}

// ---------------- row softmax over S (f32), write bf16 P in-place into row's upper half ----
// row layout: S row = 4KB; P row (bf16, len<=1024) stored at byte offset +2048 of same row.
__global__ void k_softmax(float* __restrict__ S)
{
    long rowg = blockIdx.x;                  // (b*H+h)*T + t
    int t = (int)(rowg & (T_ - 1));
    float* sp = S + rowg * T_;
    int len = ((t >> 7) + 1) << 7;           // valid+written region, multiple of 128
    int tid = threadIdx.x;
    bool act = (tid * 4) < len;
    float4 v;
    if (act) v = *(const float4*)(sp + tid*4);
    else { v.x = v.y = v.z = v.w = -1e30f; }
    float mx = fmaxf(fmaxf(v.x, v.y), fmaxf(v.z, v.w));
    #pragma unroll
    for (int o = 32; o; o >>= 1) mx = fmaxf(mx, __shfl_down(mx, o));
    __shared__ float rm[4], rs[4];
    if ((tid & 63) == 0) rm[tid >> 6] = mx;
    __syncthreads();
    mx = fmaxf(fmaxf(rm[0], rm[1]), fmaxf(rm[2], rm[3]));
    float e0 = __expf(v.x - mx), e1 = __expf(v.y - mx);
    float e2 = __expf(v.z - mx), e3 = __expf(v.w - mx);
    float sum = e0 + e1 + e2 + e3;
    #pragma unroll
    for (int o = 32; o; o >>= 1) sum += __shfl_down(sum, o);
    if ((tid & 63) == 0) rs[tid >> 6] = sum;
    __syncthreads();
    sum = rs[0] + rs[1] + rs[2] + rs[3];
    float rinv = 1.f / sum;
    if (act) {
        u16* pp = (u16*)S + rowg*2048 + 1024 + tid*4;
        ushort4 pk;
        pk.x = f2bf(e0*rinv); pk.y = f2bf(e1*rinv);
        pk.z = f2bf(e2*rinv); pk.w = f2bf(e3*rinv);
        *(ushort4*)pp = pk;
    }
}

// ---------------- MFMA GEMM: C[M][N] = A[M][K](bf16) @ Bt[N][K]^T(bf16) ----------------
// 128x128 tile, BK=32, 256 thr (4 waves 2x2, 64x64 each, 4x4 frags of 16x16x32)
// MODE: 0 bf16-out ; 1 f32 = acc+bias+res ; 2 bf16 = gelu(acc+bias) ; 3 f32 scores(+mask,*1/32) ; 4 f32 = acc+bias
template<int MODE>
__global__ void k_gemm(const u16* __restrict__ A, const u16* __restrict__ Bt,
                       void* __restrict__ Cv, const float* __restrict__ bias,
                       const float* __restrict__ res,
                       int Mm, int Nn, int Kk, long lda, long ldb, long ldc,
                       int ZH, long azb, long azh, long bzb, long bzh,
                       long czb, long czh, int causalK)
{
    const int m0 = blockIdx.y * 128, n0 = blockIdx.x * 128;
    if (MODE == 3 && n0 >= m0 + 128) return;          // fully-masked causal tile: never read
    const int z = blockIdx.z, zb = z / ZH, zh = z % ZH;
    const u16* Ab = A + (long)zb*azb + (long)zh*azh;
    const u16* Bb = Bt + (long)zb*bzb + (long)zh*bzh;
    const long coff = (long)zb*czb + (long)zh*czh;

    __shared__ alignas(16) u16 As[128][32];
    __shared__ alignas(16) u16 Bs[128][32];

    const int tid = threadIdx.x, wid = tid >> 6, lane = tid & 63;
    const int wr = wid >> 1, wc = wid & 1;
    const int srow = lane >> 2, scb = (lane & 3) << 4;   // staging: row-in-chunk, byte col
    const int fr = lane & 15, fk = (lane >> 4) << 3;     // fragment row / k-base

    f32x4 acc[4][4] = {};
    const int kEnd = causalK ? min(Kk, m0 + 128) : Kk;

    for (int k0 = 0; k0 < kEnd; k0 += 32) {
        #pragma unroll
        for (int p = 0; p < 2; ++p) {
            const int c = wid + p*4;                 // 8 chunks of 16 rows x 64B
            const int r = c*16 + srow;
            int gr = min(m0 + r, Mm - 1);
            char* ga = (char*)Ab + ((long)gr*lda + k0)*2 + scb;
            __builtin_amdgcn_global_load_lds(AS1V(ga), AS3V((char*)&As[0][0] + c*1024), 16, 0, 0);
            int gs = min(n0 + r, Nn - 1);
            char* gb = (char*)Bb + ((long)gs*ldb + k0)*2 + scb;
            __builtin_amdgcn_global_load_lds(AS1V(gb), AS3V((char*)&Bs[0][0] + c*1024), 16, 0, 0);
        }
        __syncthreads();

        bf16x8 af[4], bfv[4];
        #pragma unroll
        for (int m = 0; m < 4; ++m) af[m] = *(const bf16x8*)&As[wr*64 + m*16 + fr][fk];
        #pragma unroll
        for (int n = 0; n < 4; ++n) bfv[n] = *(const bf16x8*)&Bs[wc*64 + n*16 + fr][fk];
        #pragma unroll
        for (int m = 0; m < 4; ++m) {
            #pragma unroll
            for (int n = 0; n < 4; ++n)
                acc[m][n] = __builtin_amdgcn_mfma_f32_16x16x32_bf16(af[m], bfv[n], acc[m][n], 0, 0, 0);
        }
        __syncthreads();
    }

    const int cr0 = (lane >> 4) << 2, ccol = lane & 15;
    #pragma unroll
    for (int m = 0; m < 4; ++m) {
        #pragma unroll
        for (int r = 0; r < 4; ++r) {
            int row = m0 + wr*64 + m*16 + cr0 + r;
            if (row >= Mm) continue;
            #pragma unroll
            for (int n = 0; n < 4; ++n) {
                int col = n0 + wc*64 + n*16 + ccol;
                if (col >= Nn) continue;
                float v = acc[m][n][r];
                long idx = coff + (long)row*ldc + col;
                if constexpr (MODE == 0) {
                    ((u16*)Cv)[idx] = f2bf(v);
                } else if constexpr (MODE == 1) {
                    ((float*)Cv)[idx] = v + bias[col] + res[idx];
                } else if constexpr (MODE == 2) {
                    float tt = v + bias[col];
                    ((u16*)Cv)[idx] = f2bf(tt * 0.5f * (1.f + erff(tt * 0.70710678118f)));
                } else if constexpr (MODE == 3) {
                    ((float*)Cv)[idx] = (col <= row) ? v * 0.03125f : -1e30f;
                } else {
                    ((float*)Cv)[idx] = v + bias[col];
                }
            }
        }
    }
}

extern "C" void kernel_launch(void* const* d_in, const int* in_sizes, int n_in,
                              void* d_out, int out_size, void* d_ws, size_t ws_size,
                              hipStream_t stream)
{
    (void)in_sizes; (void)n_in; (void)out_size; (void)ws_size;
    const int*   x   = (const int*)  d_in[0];
    const float* tok = (const float*)d_in[1];
    const float* pos = (const float*)d_in[2];
    const float* Wq  = (const float*)d_in[3];
    const float* Wk  = (const float*)d_in[4];
    const float* Wv  = (const float*)d_in[5];
    const float* Wp  = (const float*)d_in[6];
    const float* bp  = (const float*)d_in[7];
    const float* g1  = (const float*)d_in[8];
    const float* bb1 = (const float*)d_in[9];
    const float* g2  = (const float*)d_in[10];
    const float* bb2 = (const float*)d_in[11];
    const float* W1  = (const float*)d_in[12];
    const float* b1  = (const float*)d_in[13];
    const float* W2  = (const float*)d_in[14];
    const float* b2  = (const float*)d_in[15];
    const float* gF  = (const float*)d_in[16];
    const float* bF  = (const float*)d_in[17];
    const float* Wo  = (const float*)d_in[18];
    const float* bo  = (const float*)d_in[19];
    float* out = (float*)d_out;

    // ---- workspace carve-up (~636 MB) ----
    char* wsp = (char*)d_ws;
    auto alloc = [&](size_t bytes) { char* p = wsp; wsp += (bytes + 255) & ~(size_t)255; return p; };
    u16* WqkvT  = (u16*)alloc((size_t)L_*3*E_*E_*2);   // [L][3E][E]  rows: q|k|v, o=h*64+d
    u16* WprojT = (u16*)alloc((size_t)L_*E_*E_*2);     // [L][E][E]
    u16* W1T    = (u16*)alloc((size_t)L_*FF_*E_*2);    // [L][FF][E]
    u16* W2T    = (u16*)alloc((size_t)L_*E_*FF_*2);    // [L][E][FF]
    u16* WoutT  = (u16*)alloc((size_t)V_*E_*2);        // [V][E]
    float* h    = (float*)alloc((size_t)M_*E_*4);      // residual stream f32
    u16* xn     = (u16*)alloc((size_t)M_*E_*2);        // LN output bf16
    u16* qkv    = (u16*)alloc((size_t)M_*3*E_*2);      // [B,T, q|k|v]
    u16* vt     = (u16*)alloc((size_t)B_*H_*HD_*T_*2); // [b,h,d,s]
    u16* attno  = (u16*)alloc((size_t)M_*E_*2);        // [b,t,h*64+d]
    u16* ffb    = (u16*)alloc((size_t)M_*FF_*2);
    float* S    = (float*)alloc((size_t)B_*H_*T_*T_*4);// scores f32; bf16 P packed in-row

    dim3 tb(32, 8);
    // ---- pack weights (f32 -> bf16, transposed to [N][K]) ----
    k_transpose<float><<<dim3(HD_/32, E_/32, L_*H_), tb, 0, stream>>>(
        Wq, WqkvT, E_, HD_, (long)HD_, (long)E_,
        H_, (long)H_*E_*HD_, (long)E_*HD_, (long)3*E_*E_, (long)HD_*E_);
    k_transpose<float><<<dim3(HD_/32, E_/32, L_*H_), tb, 0, stream>>>(
        Wk, WqkvT + (size_t)E_*E_, E_, HD_, (long)HD_, (long)E_,
        H_, (long)H_*E_*HD_, (long)E_*HD_, (long)3*E_*E_, (long)HD_*E_);
    k_transpose<float><<<dim3(HD_/32, E_/32, L_*H_), tb, 0, stream>>>(
        Wv, WqkvT + (size_t)2*E_*E_, E_, HD_, (long)HD_, (long)E_,
        H_, (long)H_*E_*HD_, (long)E_*HD_, (long)3*E_*E_, (long)HD_*E_);
    k_transpose<float><<<dim3(E_/32, E_/32, L_), tb, 0, stream>>>(
        Wp, WprojT, E_, E_, (long)E_, (long)E_, 1, (long)E_*E_, 0, (long)E_*E_, 0);
    k_transpose<float><<<dim3(FF_/32, E_/32, L_), tb, 0, stream>>>(
        W1, W1T, E_, FF_, (long)FF_, (long)E_, 1, (long)E_*FF_, 0, (long)FF_*E_, 0);
    k_transpose<float><<<dim3(E_/32, FF_/32, L_), tb, 0, stream>>>(
        W2, W2T, FF_, E_, (long)E_, (long)FF_, 1, (long)FF_*E_, 0, (long)E_*FF_, 0);
    k_transpose<float><<<dim3(V_/32, E_/32, 1), tb, 0, stream>>>(
        Wo, WoutT, E_, V_, (long)V_, (long)E_, 1, 0, 0, 0, 0);
    k_embed<<<dim3(M_*E_/4/256), dim3(256), 0, stream>>>(x, tok, pos, h);

    auto gemm = [&](int mode, const u16* A, const u16* Bt, void* C,
                    const float* bias, const float* res,
                    int Mm, int Nn, int Kk, long lda, long ldb, long ldc,
                    int gz, int ZH, long azb, long azh, long bzb, long bzh,
                    long czb, long czh, int causalK) {
        dim3 g((Nn + 127)/128, (Mm + 127)/128, gz), blk(256);
        switch (mode) {
        case 0: k_gemm<0><<<g, blk, 0, stream>>>(A, Bt, C, bias, res, Mm, Nn, Kk, lda, ldb, ldc, ZH, azb, azh, bzb, bzh, czb, czh, causalK); break;
        case 1: k_gemm<1><<<g, blk, 0, stream>>>(A, Bt, C, bias, res, Mm, Nn, Kk, lda, ldb, ldc, ZH, azb, azh, bzb, bzh, czb, czh, causalK); break;
        case 2: k_gemm<2><<<g, blk, 0, stream>>>(A, Bt, C, bias, res, Mm, Nn, Kk, lda, ldb, ldc, ZH, azb, azh, bzb, bzh, czb, czh, causalK); break;
        case 3: k_gemm<3><<<g, blk, 0, stream>>>(A, Bt, C, bias, res, Mm, Nn, Kk, lda, ldb, ldc, ZH, azb, azh, bzb, bzh, czb, czh, causalK); break;
        case 4: k_gemm<4><<<g, blk, 0, stream>>>(A, Bt, C, bias, res, Mm, Nn, Kk, lda, ldb, ldc, ZH, azb, azh, bzb, bzh, czb, czh, causalK); break;
        }
    };

    for (int l = 0; l < L_; ++l) {
        k_ln<<<dim3(M_), dim3(256), 0, stream>>>(h, g1 + (size_t)l*E_, bb1 + (size_t)l*E_, xn);
        // QKV: [M,3E] = xn[M,E] @ WqkvT^T
        gemm(0, xn, WqkvT + (size_t)l*3*E_*E_, qkv, nullptr, nullptr,
             M_, 3*E_, E_, (long)E_, (long)E_, (long)3*E_, 1, 1, 0,0,0,0,0,0, 0);
        // V^T per (b,h): vt[b,h,d,s]
        k_transpose<u16><<<dim3(HD_/32, T_/32, B_*H_), tb, 0, stream>>>(
            qkv + 2*E_, vt, T_, HD_, (long)3*E_, (long)T_,
            H_, (long)T_*3*E_, (long)HD_, (long)H_*HD_*T_, (long)HD_*T_);
        // scores: S[b,h,t,s] = q . k * (1/32), causal mask, skip fully-masked tiles
        gemm(3, qkv, qkv + E_, S, nullptr, nullptr,
             T_, T_, HD_, (long)3*E_, (long)3*E_, (long)T_,
             B_*H_, H_, (long)T_*3*E_, (long)HD_, (long)T_*3*E_, (long)HD_,
             (long)H_*T_*T_, (long)T_*T_, 0);
        k_softmax<<<dim3(B_*H_*T_), dim3(256), 0, stream>>>(S);
        // PV: attno[b,t,h*64+d] = P[t,s] @ V[s,d]  (A = in-row bf16 P, Bt = vt)
        gemm(0, (const u16*)S + 1024, vt, attno, nullptr, nullptr,
             T_, HD_, T_, 2048L, (long)T_, (long)E_,
             B_*H_, H_, (long)H_*T_*T_*2, (long)T_*T_*2,
             (long)H_*HD_*T_, (long)HD_*T_, (long)T_*E_, (long)HD_, 1);
        // proj + residual
        gemm(1, attno, WprojT + (size_t)l*E_*E_, h, bp + (size_t)l*E_, h,
             M_, E_, E_, (long)E_, (long)E_, (long)E_, 1, 1, 0,0,0,0,0,0, 0);
        k_ln<<<dim3(M_), dim3(256), 0, stream>>>(h, g2 + (size_t)l*E_, bb2 + (size_t)l*E_, xn);
        // FF1 + exact GELU
        gemm(2, xn, W1T + (size_t)l*FF_*E_, ffb, b1 + (size_t)l*FF_, nullptr,
             M_, FF_, E_, (long)E_, (long)E_, (long)FF_, 1, 1, 0,0,0,0,0,0, 0);
        // FF2 + residual
        gemm(1, ffb, W2T + (size_t)l*E_*FF_, h, b2 + (size_t)l*E_, h,
             M_, E_, FF_, (long)FF_, (long)FF_, (long)E_, 1, 1, 0,0,0,0,0,0, 0);
    }
    k_ln<<<dim3(M_), dim3(256), 0, stream>>>(h, gF, bF, xn);
    gemm(4, xn, WoutT, out, bo, nullptr,
         M_, V_, E_, (long)E_, (long)E_, (long)V_, 1, 1, 0,0,0,0,0,0, 0);
}